// Round 7
// baseline (777.355 us; speedup 1.0000x reference)
//
#include <hip/hip_runtime.h>
#include <hip/hip_bf16.h>
#include <math.h>

#define N_NODES 50000
#define N_EDGES 800000
#define NBUCK ((N_NODES + 255) / 256)   // 196
#define BCAP 6144

typedef short s16x8 __attribute__((ext_vector_type(8)));
typedef float f32x4 __attribute__((ext_vector_type(4)));

static __device__ __forceinline__ unsigned short f2bf(float x) {
    __hip_bfloat16 b = __float2bfloat16(x);
    return *(unsigned short*)&b;
}
static __device__ __forceinline__ float2 bfu2f2(unsigned int u) {
    __hip_bfloat162 b = *(__hip_bfloat162*)&u;
    return __bfloat1622float2(b);
}
static __device__ __forceinline__ unsigned int packbf2(float x, float y) {
    return (unsigned int)f2bf(x) | ((unsigned int)f2bf(y) << 16);
}

// ---------------------------------------------------------------- CSR build (bucketed)
// Pass A: scatter edges into 196 dst-buckets; within-bucket writes are sequential.
__global__ void k_bucket(const int* __restrict__ src, const int* __restrict__ dst,
                         int* __restrict__ bcnt, unsigned int* __restrict__ bke) {
    int e = blockIdx.x * blockDim.x + threadIdx.x;
    if (e >= N_EDGES) return;
    int d = dst[e];
    int b = d >> 8;
    int pos = atomicAdd(&bcnt[b], 1);
    if (pos < BCAP) bke[b * BCAP + pos] = (unsigned int)src[e] | ((unsigned int)(d & 255) << 16);
}

// Pass B: exclusive scan over 196 bucket counts (single block).
__global__ __launch_bounds__(256) void k_bscan(const int* __restrict__ bcnt, int* __restrict__ bbase) {
    __shared__ int lds[256];
    int t = threadIdx.x;
    int v = (t < NBUCK) ? min(bcnt[t], BCAP) : 0;
    lds[t] = v;
    __syncthreads();
    for (int off = 1; off < 256; off <<= 1) {
        int x = (t >= off) ? lds[t - off] : 0;
        __syncthreads();
        lds[t] += x;
        __syncthreads();
    }
    if (t < NBUCK) bbase[t] = lds[t] - v;
}

// Pass C: per-bucket LDS counting sort -> dst-sorted CSR + row_start, coalesced writes.
__global__ __launch_bounds__(256) void k_binsort(const unsigned int* __restrict__ bke,
                                                 const int* __restrict__ bcnt,
                                                 const int* __restrict__ bbase,
                                                 int* __restrict__ csr,
                                                 int* __restrict__ row_start) {
    __shared__ int cnt_l[256];
    __shared__ int scan_l[256];
    __shared__ int cursor[256];
    __shared__ int stage[BCAP];
    const int b = blockIdx.x;
    const int t = threadIdx.x;
    const int nb = min(bcnt[b], BCAP);
    const unsigned int* ed = bke + (size_t)b * BCAP;
    cnt_l[t] = 0;
    __syncthreads();
    for (int i = t; i < nb; i += 256) atomicAdd(&cnt_l[(ed[i] >> 16) & 255], 1);
    __syncthreads();
    int v = cnt_l[t];
    scan_l[t] = v;
    __syncthreads();
    for (int off = 1; off < 256; off <<= 1) {
        int x = (t >= off) ? scan_l[t - off] : 0;
        __syncthreads();
        scan_l[t] += x;
        __syncthreads();
    }
    int excl = scan_l[t] - v;
    cursor[t] = excl;
    const int base = bbase[b];
    int node = b * 256 + t;
    if (node <= N_NODES) row_start[node] = base + excl;
    __syncthreads();
    for (int i = t; i < nb; i += 256) {
        unsigned int u = ed[i];
        int pos = atomicAdd(&cursor[(u >> 16) & 255], 1);
        stage[pos] = (int)(u & 0xFFFF);
    }
    __syncthreads();
    for (int i = t; i < nb; i += 256) csr[base + i] = stage[i];
}

// ---------------------------------------------------------------- bf16 prep
#define FEATN (N_NODES * 256)
#define O_WL_E1 (FEATN)
#define O_WR_E1 (FEATN + 32768)
#define O_WL_E2 (FEATN + 65536)
#define O_WR_E2 (FEATN + 81920)
#define O_W_FC  (FEATN + 98304)
#define O_WL_D1 (FEATN + 114688)
#define O_WR_D1 (FEATN + 131072)
#define O_D2    (FEATN + 147456)   // 256 rows x 256: row n = Wl_d2[n] || Wr_d2[n]
#define PREP_TOT (FEATN + 212992)

__global__ __launch_bounds__(256) void k_prep(const float* __restrict__ feat,
                                              const float* __restrict__ wle1, const float* __restrict__ wre1,
                                              const float* __restrict__ wle2, const float* __restrict__ wre2,
                                              const float* __restrict__ wfc,
                                              const float* __restrict__ wld1, const float* __restrict__ wrd1,
                                              const float* __restrict__ wld2, const float* __restrict__ wrd2,
                                              unsigned short* __restrict__ dstp) {
    const int tot4 = PREP_TOT / 4;
    for (int i = blockIdx.x * blockDim.x + threadIdx.x; i < tot4; i += gridDim.x * blockDim.x) {
        int e = i * 4;
        const float* s;
        int off;
        if      (e < O_WL_E1) { s = feat; off = e; }
        else if (e < O_WR_E1) { s = wle1; off = e - O_WL_E1; }
        else if (e < O_WL_E2) { s = wre1; off = e - O_WR_E1; }
        else if (e < O_WR_E2) { s = wle2; off = e - O_WL_E2; }
        else if (e < O_W_FC)  { s = wre2; off = e - O_WR_E2; }
        else if (e < O_WL_D1) { s = wfc;  off = e - O_W_FC; }
        else if (e < O_WR_D1) { s = wld1; off = e - O_WL_D1; }
        else if (e < O_D2)    { s = wrd1; off = e - O_WR_D1; }
        else {
            int rel = e - O_D2;
            int row = rel >> 8, half = (rel >> 7) & 1, col = rel & 127;
            s = half ? wrd2 : wld2;
            off = row * 128 + col;
        }
        float4 v = *(const float4*)&s[off];
        ushort4 u;
        u.x = f2bf(v.x); u.y = f2bf(v.y); u.z = f2bf(v.z); u.w = f2bf(v.w);
        *(ushort4*)&dstp[e] = u;
    }
}

// ---------------------------------------------------------------- MFMA GEMM v3
// Y[N,Ystride] cols [128*blockIdx.y, +128) = X[N,K] @ W[rows 128*y..+128][K]^T (+bias)
// W in LDS (XOR-swizzled); X direct global->VGPR with depth-1 prefetch; full k-unroll.
template <int K>
__global__ __launch_bounds__(256) void k_gmm2(const unsigned short* __restrict__ X,
                                              const unsigned short* __restrict__ W,
                                              const float* __restrict__ bias0,
                                              const float* __restrict__ bias1,
                                              unsigned short* __restrict__ Y,
                                              int N, int Ystride) {
    constexpr int CH = K / 8;
    __shared__ unsigned short Ws[128 * K];
    const unsigned short* Wsrc = W + (size_t)blockIdx.y * 128 * K;
    for (int idx = threadIdx.x; idx < 128 * CH; idx += 256) {
        int n = idx / CH, c = idx % CH;
        uint4 v = *(const uint4*)&Wsrc[n * K + c * 8];
        int cs = c ^ (n & 15);
        *(uint4*)&Ws[n * K + cs * 8] = v;
    }
    __syncthreads();

    const int wid = threadIdx.x >> 6, lane = threadIdx.x & 63;
    const int row0 = blockIdx.x * 128 + wid * 32;
    const int lrow = lane & 15;
    const int lk8  = lane >> 4;
    f32x4 acc[2][8] = {};

    s16x8 a_cur[2];
#pragma unroll
    for (int i = 0; i < 2; i++) {
        int r = row0 + i * 16 + lrow;
        s16x8 av = {};
        if (r < N) av = *(const s16x8*)&X[(size_t)r * K + lk8 * 8];
        a_cur[i] = av;
    }

#pragma unroll
    for (int ks = 0; ks < K; ks += 32) {
        s16x8 a_nxt[2] = {};
        if (ks + 32 < K) {
#pragma unroll
            for (int i = 0; i < 2; i++) {
                int r = row0 + i * 16 + lrow;
                if (r < N) a_nxt[i] = *(const s16x8*)&X[(size_t)r * K + ks + 32 + lk8 * 8];
            }
        }
#pragma unroll
        for (int nf = 0; nf < 8; nf++) {
            int n = nf * 16 + lrow;
            int c = (ks >> 3) + lk8;
            int cs = c ^ (n & 15);
            s16x8 b = *(const s16x8*)&Ws[n * K + cs * 8];
            acc[0][nf] = __builtin_amdgcn_mfma_f32_16x16x32_bf16(a_cur[0], b, acc[0][nf], 0, 0, 0);
            acc[1][nf] = __builtin_amdgcn_mfma_f32_16x16x32_bf16(a_cur[1], b, acc[1][nf], 0, 0, 0);
        }
        a_cur[0] = a_nxt[0];
        a_cur[1] = a_nxt[1];
    }

    const float* bias = (blockIdx.y == 0) ? bias0 : bias1;
    const int ccol = lane & 15, crow0 = (lane >> 4) * 4;
    const int ycol0 = blockIdx.y * 128;
#pragma unroll
    for (int nf = 0; nf < 8; nf++) {
        int lcol = nf * 16 + ccol;
        float bv = bias ? bias[lcol] : 0.0f;
#pragma unroll
        for (int i = 0; i < 2; i++) {
#pragma unroll
            for (int j = 0; j < 4; j++) {
                int grow = row0 + i * 16 + crow0 + j;
                if (grow < N) Y[(size_t)grow * Ystride + ycol0 + lcol] = f2bf(acc[i][nf][j] + bv);
            }
        }
    }
}

// ------------------------------------------- gather-aggregate + finalize (128-dim, CSR)
// uint4 lanes: lane (q = L&15, sub = L>>4) handles cols [8q,8q+8), edge subgroup sub.
template <bool WRITE_F32>
__global__ __launch_bounds__(256) void k_aggfin4(const uint4* __restrict__ TP,
                                                 const int* __restrict__ csr,
                                                 const int* __restrict__ row_start,
                                                 float* __restrict__ OUTF,
                                                 uint4* __restrict__ OUTB,
                                                 int ostride4, int ooff4) {
    const int wave = (blockIdx.x * blockDim.x + threadIdx.x) >> 6;
    const int lane = threadIdx.x & 63;
    if (wave >= N_NODES) return;
    const int q = lane & 15, sub = lane >> 4;
    const int base = row_start[wave];
    const int deg = row_start[wave + 1] - base;
    float acc[8] = {};
    int i = sub;
    for (; i + 4 < deg; i += 8) {
        int nb0 = csr[base + i], nb1 = csr[base + i + 4];
        uint4 v0 = TP[(size_t)nb0 * 32 + q];
        uint4 v1 = TP[(size_t)nb1 * 32 + q];
        float2 a0 = bfu2f2(v0.x), a1 = bfu2f2(v0.y), a2 = bfu2f2(v0.z), a3 = bfu2f2(v0.w);
        float2 b0 = bfu2f2(v1.x), b1 = bfu2f2(v1.y), b2 = bfu2f2(v1.z), b3 = bfu2f2(v1.w);
        acc[0] += a0.x + b0.x; acc[1] += a0.y + b0.y;
        acc[2] += a1.x + b1.x; acc[3] += a1.y + b1.y;
        acc[4] += a2.x + b2.x; acc[5] += a2.y + b2.y;
        acc[6] += a3.x + b3.x; acc[7] += a3.y + b3.y;
    }
    if (i < deg) {
        int nb = csr[base + i];
        uint4 v = TP[(size_t)nb * 32 + q];
        float2 a0 = bfu2f2(v.x), a1 = bfu2f2(v.y), a2 = bfu2f2(v.z), a3 = bfu2f2(v.w);
        acc[0] += a0.x; acc[1] += a0.y; acc[2] += a1.x; acc[3] += a1.y;
        acc[4] += a2.x; acc[5] += a2.y; acc[6] += a3.x; acc[7] += a3.y;
    }
#pragma unroll
    for (int k = 0; k < 8; k++) {
        acc[k] += __shfl_xor(acc[k], 16);
        acc[k] += __shfl_xor(acc[k], 32);
    }
    const float inv = 1.0f / fmaxf((float)deg, 1.0f);
    uint4 pv = TP[(size_t)wave * 32 + 16 + q];
    float2 p0 = bfu2f2(pv.x), p1 = bfu2f2(pv.y), p2 = bfu2f2(pv.z), p3 = bfu2f2(pv.w);
    float o[8];
    o[0] = p0.x + inv * acc[0]; o[1] = p0.y + inv * acc[1];
    o[2] = p1.x + inv * acc[2]; o[3] = p1.y + inv * acc[3];
    o[4] = p2.x + inv * acc[4]; o[5] = p2.y + inv * acc[5];
    o[6] = p3.x + inv * acc[6]; o[7] = p3.y + inv * acc[7];
    float ss = 0.0f;
#pragma unroll
    for (int k = 0; k < 8; k++) ss += o[k] * o[k];
    ss += __shfl_xor(ss, 1); ss += __shfl_xor(ss, 2);
    ss += __shfl_xor(ss, 4); ss += __shfl_xor(ss, 8);
    float r = 1.0f / fmaxf(sqrtf(ss), 1e-12f);
#pragma unroll
    for (int k = 0; k < 8; k++) o[k] *= r;
    if (lane < 16) {
        if constexpr (WRITE_F32) {
            ((float4*)OUTF)[(size_t)wave * 32 + q * 2]     = make_float4(o[0], o[1], o[2], o[3]);
            ((float4*)OUTF)[(size_t)wave * 32 + q * 2 + 1] = make_float4(o[4], o[5], o[6], o[7]);
        }
        uint4 u;
        u.x = packbf2(o[0], o[1]); u.y = packbf2(o[2], o[3]);
        u.z = packbf2(o[4], o[5]); u.w = packbf2(o[6], o[7]);
        OUTB[(size_t)wave * ostride4 + ooff4 + q] = u;
    }
}

// ------------------------------------------- pure aggregation (bf16 in/out, 128-dim, CSR)
__global__ __launch_bounds__(256) void k_agg4(const uint4* __restrict__ IN,
                                              const int* __restrict__ csr,
                                              const int* __restrict__ row_start,
                                              uint4* __restrict__ OUT,
                                              int istride4, int ioff4, int ostride4, int ooff4) {
    const int wave = (blockIdx.x * blockDim.x + threadIdx.x) >> 6;
    const int lane = threadIdx.x & 63;
    if (wave >= N_NODES) return;
    const int q = lane & 15, sub = lane >> 4;
    const int base = row_start[wave];
    const int deg = row_start[wave + 1] - base;
    float acc[8] = {};
    int i = sub;
    for (; i + 4 < deg; i += 8) {
        int nb0 = csr[base + i], nb1 = csr[base + i + 4];
        uint4 v0 = IN[(size_t)nb0 * istride4 + ioff4 + q];
        uint4 v1 = IN[(size_t)nb1 * istride4 + ioff4 + q];
        float2 a0 = bfu2f2(v0.x), a1 = bfu2f2(v0.y), a2 = bfu2f2(v0.z), a3 = bfu2f2(v0.w);
        float2 b0 = bfu2f2(v1.x), b1 = bfu2f2(v1.y), b2 = bfu2f2(v1.z), b3 = bfu2f2(v1.w);
        acc[0] += a0.x + b0.x; acc[1] += a0.y + b0.y;
        acc[2] += a1.x + b1.x; acc[3] += a1.y + b1.y;
        acc[4] += a2.x + b2.x; acc[5] += a2.y + b2.y;
        acc[6] += a3.x + b3.x; acc[7] += a3.y + b3.y;
    }
    if (i < deg) {
        int nb = csr[base + i];
        uint4 v = IN[(size_t)nb * istride4 + ioff4 + q];
        float2 a0 = bfu2f2(v.x), a1 = bfu2f2(v.y), a2 = bfu2f2(v.z), a3 = bfu2f2(v.w);
        acc[0] += a0.x; acc[1] += a0.y; acc[2] += a1.x; acc[3] += a1.y;
        acc[4] += a2.x; acc[5] += a2.y; acc[6] += a3.x; acc[7] += a3.y;
    }
#pragma unroll
    for (int k = 0; k < 8; k++) {
        acc[k] += __shfl_xor(acc[k], 16);
        acc[k] += __shfl_xor(acc[k], 32);
    }
    const float inv = 1.0f / fmaxf((float)deg, 1.0f);
    if (lane < 16) {
        uint4 u;
        u.x = packbf2(inv * acc[0], inv * acc[1]);
        u.y = packbf2(inv * acc[2], inv * acc[3]);
        u.z = packbf2(inv * acc[4], inv * acc[5]);
        u.w = packbf2(inv * acc[6], inv * acc[7]);
        OUT[(size_t)wave * ostride4 + ooff4 + q] = u;
    }
}

// ------------------------------------------- row L2-normalize bf16[N][256] -> f32
__global__ __launch_bounds__(256) void k_norm256(const unsigned short* __restrict__ Rb,
                                                 float* __restrict__ OUT) {
    const int wave = (blockIdx.x * blockDim.x + threadIdx.x) >> 6;
    const int lane = threadIdx.x & 63;
    if (wave >= N_NODES) return;
    ushort4 v = ((const ushort4*)Rb)[(size_t)wave * 64 + lane];
    float x0 = __bfloat162float(*(__hip_bfloat16*)&v.x);
    float x1 = __bfloat162float(*(__hip_bfloat16*)&v.y);
    float x2 = __bfloat162float(*(__hip_bfloat16*)&v.z);
    float x3 = __bfloat162float(*(__hip_bfloat16*)&v.w);
    float ss = x0 * x0 + x1 * x1 + x2 * x2 + x3 * x3;
#pragma unroll
    for (int off = 32; off > 0; off >>= 1) ss += __shfl_xor(ss, off);
    float r = 1.0f / fmaxf(sqrtf(ss), 1e-12f);
    float4 o = make_float4(x0 * r, x1 * r, x2 * r, x3 * r);
    ((float4*)OUT)[(size_t)wave * 64 + lane] = o;
}

// ---------------------------------------------------------------- launch
extern "C" void kernel_launch(void* const* d_in, const int* in_sizes, int n_in,
                              void* d_out, int out_size, void* d_ws, size_t ws_size,
                              hipStream_t stream) {
    const float* feat  = (const float*)d_in[0];
    const int*   ei    = (const int*)d_in[1];
    const int*   src   = ei;
    const int*   dst   = ei + N_EDGES;
    const float* Wl_e1 = (const float*)d_in[2];
    const float* bl_e1 = (const float*)d_in[3];
    const float* Wr_e1 = (const float*)d_in[4];
    const float* Wl_e2 = (const float*)d_in[5];
    const float* bl_e2 = (const float*)d_in[6];
    const float* Wr_e2 = (const float*)d_in[7];
    const float* W_fc  = (const float*)d_in[8];
    const float* b_fc  = (const float*)d_in[9];
    const float* Wl_d1 = (const float*)d_in[10];
    const float* bl_d1 = (const float*)d_in[11];
    const float* Wr_d1 = (const float*)d_in[12];
    const float* Wl_d2 = (const float*)d_in[13];
    const float* bl_d2 = (const float*)d_in[14];
    const float* Wr_d2 = (const float*)d_in[15];

    char* w = (char*)d_ws;
    auto alloc = [&](size_t bytes) -> void* {
        void* p = (void*)w;
        w += (bytes + 255) & ~(size_t)255;
        return p;
    };
    int* bcnt      = (int*)alloc((size_t)NBUCK * 4);
    int* bbase     = (int*)alloc((size_t)NBUCK * 4);
    unsigned int* bke = (unsigned int*)alloc((size_t)NBUCK * BCAP * 4);
    int* csr       = (int*)alloc((size_t)N_EDGES * 4);
    int* row_start = (int*)alloc((size_t)(N_NODES + 1) * 4);
    unsigned short* bfpool = (unsigned short*)alloc((size_t)PREP_TOT * 2);
    unsigned short* TP   = (unsigned short*)alloc((size_t)N_NODES * 256 * 2);  // [N][256] T||P
    unsigned short* hb   = (unsigned short*)alloc((size_t)N_NODES * 128 * 2);  // h, then xfc
    unsigned short* x1b  = (unsigned short*)alloc((size_t)N_NODES * 128 * 2);
    unsigned short* X2   = (unsigned short*)alloc((size_t)N_NODES * 256 * 2);  // [aggm || hd1]
    unsigned short* R1b  = (unsigned short*)alloc((size_t)N_NODES * 256 * 2);

    unsigned short* featb = bfpool;
    float* x1     = (float*)d_out;
    float* x1_rec = (float*)d_out + (size_t)N_NODES * 128;

    hipMemsetAsync(bcnt, 0, (size_t)NBUCK * 4, stream);

    const int EB = (N_EDGES + 255) / 256;
    k_prep<<<2048, 256, 0, stream>>>(feat, Wl_e1, Wr_e1, Wl_e2, Wr_e2, W_fc, Wl_d1, Wr_d1, Wl_d2, Wr_d2, bfpool);
    k_bucket<<<EB, 256, 0, stream>>>(src, dst, bcnt, bke);
    k_bscan<<<1, 256, 0, stream>>>(bcnt, bbase);
    k_binsort<<<NBUCK, 256, 0, stream>>>(bke, bcnt, bbase, csr, row_start);

    const int NB128 = (N_NODES + 127) / 128;  // 391
    const int WPB   = (N_NODES * 64 + 255) / 256;

    // ---- encoder conv1: 256 -> 128 (fused T||P)
    k_gmm2<256><<<dim3(NB128, 2), 256, 0, stream>>>(featb, bfpool + O_WL_E1, nullptr, bl_e1, TP, N_NODES, 256);
    k_aggfin4<false><<<WPB, 256, 0, stream>>>((const uint4*)TP, csr, row_start, nullptr, (uint4*)hb, 16, 0);
    // ---- encoder conv2: 128 -> 128  (x1 f32 + bf16 copy)
    k_gmm2<128><<<dim3(NB128, 2), 256, 0, stream>>>(hb, bfpool + O_WL_E2, nullptr, bl_e2, TP, N_NODES, 256);
    k_aggfin4<true><<<WPB, 256, 0, stream>>>((const uint4*)TP, csr, row_start, x1, (uint4*)x1b, 16, 0);
    // ---- bottleneck fc: 128 -> 128 (hb dead -> xfc)
    k_gmm2<128><<<dim3(NB128, 1), 256, 0, stream>>>(x1b, bfpool + O_W_FC, b_fc, nullptr, hb, N_NODES, 128);
    // ---- decoder conv1: 128 -> 128 (hd1 -> X2 cols 128-255)
    k_gmm2<128><<<dim3(NB128, 2), 256, 0, stream>>>(hb, bfpool + O_WL_D1, nullptr, bl_d1, TP, N_NODES, 256);
    k_aggfin4<false><<<WPB, 256, 0, stream>>>((const uint4*)TP, csr, row_start, nullptr, (uint4*)X2, 32, 16);
    // ---- decoder conv2: 128 -> 256 (agg-first into X2 cols 0-127; single K=256 GEMM)
    k_agg4<<<WPB, 256, 0, stream>>>((const uint4*)X2, csr, row_start, (uint4*)X2, 32, 16, 32, 0);
    k_gmm2<256><<<dim3(NB128, 2), 256, 0, stream>>>(X2, bfpool + O_D2, bl_d2, bl_d2 + 128, R1b, N_NODES, 256);
    k_norm256<<<WPB, 256, 0, stream>>>(R1b, x1_rec);
}

// Round 8
// 345.234 us; speedup vs baseline: 2.2517x; 2.2517x over previous
//
#include <hip/hip_runtime.h>
#include <hip/hip_bf16.h>
#include <math.h>

#define N_NODES 50000
#define N_EDGES 800000
#define SLOT_CAP 64

typedef short s16x8 __attribute__((ext_vector_type(8)));
typedef float f32x4 __attribute__((ext_vector_type(4)));

static __device__ __forceinline__ unsigned short f2bf(float x) {
    __hip_bfloat16 b = __float2bfloat16(x);
    return *(unsigned short*)&b;
}
static __device__ __forceinline__ float2 bfu2f2(unsigned int u) {
    __hip_bfloat162 b = *(__hip_bfloat162*)&u;
    return __bfloat1622float2(b);
}
static __device__ __forceinline__ unsigned int packbf2(float x, float y) {
    return (unsigned int)f2bf(x) | ((unsigned int)f2bf(y) << 16);
}

// ---------------------------------------------------------------- slot fill
// One pass: histogram + scatter into fixed 64-entry bins. cnt must be 0 on entry.
__global__ void k_fillslot(const int* __restrict__ src, const int* __restrict__ dst,
                           int* __restrict__ cnt, int* __restrict__ slots) {
    int e = blockIdx.x * blockDim.x + threadIdx.x;
    if (e >= N_EDGES) return;
    int d = dst[e];
    int pos = atomicAdd(&cnt[d], 1);
    if (pos < SLOT_CAP) slots[d * SLOT_CAP + pos] = src[e];
}

// ---------------------------------------------------------------- bf16 prep
#define FEATN (N_NODES * 256)
#define O_WL_E1 (FEATN)
#define O_WR_E1 (FEATN + 32768)
#define O_WL_E2 (FEATN + 65536)
#define O_WR_E2 (FEATN + 81920)
#define O_W_FC  (FEATN + 98304)
#define O_WL_D1 (FEATN + 114688)
#define O_WR_D1 (FEATN + 131072)
#define O_D2    (FEATN + 147456)   // 256 rows x 256: row n = Wl_d2[n] || Wr_d2[n]
#define PREP_TOT (FEATN + 212992)

__global__ __launch_bounds__(256) void k_prep(const float* __restrict__ feat,
                                              const float* __restrict__ wle1, const float* __restrict__ wre1,
                                              const float* __restrict__ wle2, const float* __restrict__ wre2,
                                              const float* __restrict__ wfc,
                                              const float* __restrict__ wld1, const float* __restrict__ wrd1,
                                              const float* __restrict__ wld2, const float* __restrict__ wrd2,
                                              unsigned short* __restrict__ dstp) {
    const int tot4 = PREP_TOT / 4;
    for (int i = blockIdx.x * blockDim.x + threadIdx.x; i < tot4; i += gridDim.x * blockDim.x) {
        int e = i * 4;
        const float* s;
        int off;
        if      (e < O_WL_E1) { s = feat; off = e; }
        else if (e < O_WR_E1) { s = wle1; off = e - O_WL_E1; }
        else if (e < O_WL_E2) { s = wre1; off = e - O_WR_E1; }
        else if (e < O_WR_E2) { s = wle2; off = e - O_WL_E2; }
        else if (e < O_W_FC)  { s = wre2; off = e - O_WR_E2; }
        else if (e < O_WL_D1) { s = wfc;  off = e - O_W_FC; }
        else if (e < O_WR_D1) { s = wld1; off = e - O_WL_D1; }
        else if (e < O_D2)    { s = wrd1; off = e - O_WR_D1; }
        else {
            int rel = e - O_D2;
            int row = rel >> 8, half = (rel >> 7) & 1, col = rel & 127;
            s = half ? wrd2 : wld2;
            off = row * 128 + col;
        }
        float4 v = *(const float4*)&s[off];
        ushort4 u;
        u.x = f2bf(v.x); u.y = f2bf(v.y); u.z = f2bf(v.z); u.w = f2bf(v.w);
        *(ushort4*)&dstp[e] = u;
    }
}

// ---------------------------------------------------------------- MFMA GEMM (depth-1 X prefetch)
// Y[N,Ystride] cols [128*blockIdx.y, +128) = X[N,K] @ W[rows 128*y..+128][K]^T (+bias)
template <int K>
__global__ __launch_bounds__(256) void k_gmm2(const unsigned short* __restrict__ X,
                                              const unsigned short* __restrict__ W,
                                              const float* __restrict__ bias0,
                                              const float* __restrict__ bias1,
                                              unsigned short* __restrict__ Y,
                                              int N, int Ystride) {
    constexpr int CH = K / 8;
    __shared__ unsigned short Ws[128 * K];
    const unsigned short* Wsrc = W + (size_t)blockIdx.y * 128 * K;
    for (int idx = threadIdx.x; idx < 128 * CH; idx += 256) {
        int n = idx / CH, c = idx % CH;
        uint4 v = *(const uint4*)&Wsrc[n * K + c * 8];
        int cs = c ^ (n & 15);
        *(uint4*)&Ws[n * K + cs * 8] = v;
    }
    __syncthreads();

    const int wid = threadIdx.x >> 6, lane = threadIdx.x & 63;
    const int row0 = blockIdx.x * 128 + wid * 32;
    const int lrow = lane & 15;
    const int lk8  = lane >> 4;
    f32x4 acc[2][8] = {};

    s16x8 a_cur[2];
#pragma unroll
    for (int i = 0; i < 2; i++) {
        int r = row0 + i * 16 + lrow;
        s16x8 av = {};
        if (r < N) av = *(const s16x8*)&X[(size_t)r * K + lk8 * 8];
        a_cur[i] = av;
    }

#pragma unroll
    for (int ks = 0; ks < K; ks += 32) {
        s16x8 a_nxt[2] = {};
        if (ks + 32 < K) {
#pragma unroll
            for (int i = 0; i < 2; i++) {
                int r = row0 + i * 16 + lrow;
                if (r < N) a_nxt[i] = *(const s16x8*)&X[(size_t)r * K + ks + 32 + lk8 * 8];
            }
        }
#pragma unroll
        for (int nf = 0; nf < 8; nf++) {
            int n = nf * 16 + lrow;
            int c = (ks >> 3) + lk8;
            int cs = c ^ (n & 15);
            s16x8 b = *(const s16x8*)&Ws[n * K + cs * 8];
            acc[0][nf] = __builtin_amdgcn_mfma_f32_16x16x32_bf16(a_cur[0], b, acc[0][nf], 0, 0, 0);
            acc[1][nf] = __builtin_amdgcn_mfma_f32_16x16x32_bf16(a_cur[1], b, acc[1][nf], 0, 0, 0);
        }
        a_cur[0] = a_nxt[0];
        a_cur[1] = a_nxt[1];
    }

    const float* bias = (blockIdx.y == 0) ? bias0 : bias1;
    const int ccol = lane & 15, crow0 = (lane >> 4) * 4;
    const int ycol0 = blockIdx.y * 128;
#pragma unroll
    for (int nf = 0; nf < 8; nf++) {
        int lcol = nf * 16 + ccol;
        float bv = bias ? bias[lcol] : 0.0f;
#pragma unroll
        for (int i = 0; i < 2; i++) {
#pragma unroll
            for (int j = 0; j < 4; j++) {
                int grow = row0 + i * 16 + crow0 + j;
                if (grow < N) Y[(size_t)grow * Ystride + ycol0 + lcol] = f2bf(acc[i][nf][j] + bv);
            }
        }
    }
}

// ------------------------------------------- fused final GEMM (K=256, 256 cols) + L2 norm
// OUT[N][256] f32 = l2normalize_row(X[N,256] @ W[256,256]^T + bias)
__global__ __launch_bounds__(256) void k_gmmn(const unsigned short* __restrict__ X,
                                              const unsigned short* __restrict__ W,
                                              const float* __restrict__ bias,
                                              float* __restrict__ OUT, int N) {
    __shared__ unsigned short Ws[128 * 256];
    const int wid = threadIdx.x >> 6, lane = threadIdx.x & 63;
    const int row0 = blockIdx.x * 128 + wid * 32;
    const int lrow = lane & 15;
    const int lk8  = lane >> 4;
    const int ccol = lane & 15, crow0 = (lane >> 4) * 4;
    f32x4 acc[2][2][8] = {};  // [half][i][nf]

#pragma unroll
    for (int half = 0; half < 2; half++) {
        __syncthreads();
        const unsigned short* Wsrc = W + (size_t)half * 128 * 256;
        for (int idx = threadIdx.x; idx < 128 * 32; idx += 256) {
            int n = idx / 32, c = idx % 32;
            uint4 v = *(const uint4*)&Wsrc[n * 256 + c * 8];
            int cs = c ^ (n & 15);
            *(uint4*)&Ws[n * 256 + cs * 8] = v;
        }
        __syncthreads();

        s16x8 a_cur[2];
#pragma unroll
        for (int i = 0; i < 2; i++) {
            int r = row0 + i * 16 + lrow;
            s16x8 av = {};
            if (r < N) av = *(const s16x8*)&X[(size_t)r * 256 + lk8 * 8];
            a_cur[i] = av;
        }
#pragma unroll
        for (int ks = 0; ks < 256; ks += 32) {
            s16x8 a_nxt[2] = {};
            if (ks + 32 < 256) {
#pragma unroll
                for (int i = 0; i < 2; i++) {
                    int r = row0 + i * 16 + lrow;
                    if (r < N) a_nxt[i] = *(const s16x8*)&X[(size_t)r * 256 + ks + 32 + lk8 * 8];
                }
            }
#pragma unroll
            for (int nf = 0; nf < 8; nf++) {
                int n = nf * 16 + lrow;
                int c = (ks >> 3) + lk8;
                int cs = c ^ (n & 15);
                s16x8 b = *(const s16x8*)&Ws[n * 256 + cs * 8];
                acc[half][0][nf] = __builtin_amdgcn_mfma_f32_16x16x32_bf16(a_cur[0], b, acc[half][0][nf], 0, 0, 0);
                acc[half][1][nf] = __builtin_amdgcn_mfma_f32_16x16x32_bf16(a_cur[1], b, acc[half][1][nf], 0, 0, 0);
            }
            a_cur[0] = a_nxt[0];
            a_cur[1] = a_nxt[1];
        }
    }

    // add bias
#pragma unroll
    for (int half = 0; half < 2; half++)
#pragma unroll
        for (int nf = 0; nf < 8; nf++) {
            float bv = bias[half * 128 + nf * 16 + ccol];
#pragma unroll
            for (int i = 0; i < 2; i++)
#pragma unroll
                for (int j = 0; j < 4; j++) acc[half][i][nf][j] += bv;
        }
    // row sums of squares + butterfly over the 16 col-lanes
    float rs[2][4];
#pragma unroll
    for (int i = 0; i < 2; i++)
#pragma unroll
        for (int j = 0; j < 4; j++) {
            float ss = 0.0f;
#pragma unroll
            for (int half = 0; half < 2; half++)
#pragma unroll
                for (int nf = 0; nf < 8; nf++) ss += acc[half][i][nf][j] * acc[half][i][nf][j];
            ss += __shfl_xor(ss, 1); ss += __shfl_xor(ss, 2);
            ss += __shfl_xor(ss, 4); ss += __shfl_xor(ss, 8);
            rs[i][j] = 1.0f / fmaxf(sqrtf(ss), 1e-12f);
        }
    // write normalized f32
#pragma unroll
    for (int i = 0; i < 2; i++)
#pragma unroll
        for (int j = 0; j < 4; j++) {
            int grow = row0 + i * 16 + crow0 + j;
            if (grow < N) {
                float r = rs[i][j];
#pragma unroll
                for (int half = 0; half < 2; half++)
#pragma unroll
                    for (int nf = 0; nf < 8; nf++)
                        OUT[(size_t)grow * 256 + half * 128 + nf * 16 + ccol] = acc[half][i][nf][j] * r;
            }
        }
}

// ------------------------------------------- gather-aggregate + finalize (128-dim)
template <bool WRITE_F32>
__global__ __launch_bounds__(256) void k_aggfin4(const uint4* __restrict__ TP,
                                                 const int* __restrict__ slots,
                                                 const int* __restrict__ cnt,
                                                 float* __restrict__ OUTF,
                                                 uint4* __restrict__ OUTB,
                                                 int ostride4, int ooff4) {
    const int wave = (blockIdx.x * blockDim.x + threadIdx.x) >> 6;
    const int lane = threadIdx.x & 63;
    if (wave >= N_NODES) return;
    const int q = lane & 15, sub = lane >> 4;
    int deg = cnt[wave];
    deg = min(deg, SLOT_CAP);
    const int base = wave * SLOT_CAP;
    float acc[8] = {};
    int i = sub;
    for (; i + 4 < deg; i += 8) {
        int nb0 = slots[base + i], nb1 = slots[base + i + 4];
        uint4 v0 = TP[(size_t)nb0 * 32 + q];
        uint4 v1 = TP[(size_t)nb1 * 32 + q];
        float2 a0 = bfu2f2(v0.x), a1 = bfu2f2(v0.y), a2 = bfu2f2(v0.z), a3 = bfu2f2(v0.w);
        float2 b0 = bfu2f2(v1.x), b1 = bfu2f2(v1.y), b2 = bfu2f2(v1.z), b3 = bfu2f2(v1.w);
        acc[0] += a0.x + b0.x; acc[1] += a0.y + b0.y;
        acc[2] += a1.x + b1.x; acc[3] += a1.y + b1.y;
        acc[4] += a2.x + b2.x; acc[5] += a2.y + b2.y;
        acc[6] += a3.x + b3.x; acc[7] += a3.y + b3.y;
    }
    if (i < deg) {
        int nb = slots[base + i];
        uint4 v = TP[(size_t)nb * 32 + q];
        float2 a0 = bfu2f2(v.x), a1 = bfu2f2(v.y), a2 = bfu2f2(v.z), a3 = bfu2f2(v.w);
        acc[0] += a0.x; acc[1] += a0.y; acc[2] += a1.x; acc[3] += a1.y;
        acc[4] += a2.x; acc[5] += a2.y; acc[6] += a3.x; acc[7] += a3.y;
    }
#pragma unroll
    for (int k = 0; k < 8; k++) {
        acc[k] += __shfl_xor(acc[k], 16);
        acc[k] += __shfl_xor(acc[k], 32);
    }
    const float inv = 1.0f / fmaxf((float)deg, 1.0f);
    uint4 pv = TP[(size_t)wave * 32 + 16 + q];
    float2 p0 = bfu2f2(pv.x), p1 = bfu2f2(pv.y), p2 = bfu2f2(pv.z), p3 = bfu2f2(pv.w);
    float o[8];
    o[0] = p0.x + inv * acc[0]; o[1] = p0.y + inv * acc[1];
    o[2] = p1.x + inv * acc[2]; o[3] = p1.y + inv * acc[3];
    o[4] = p2.x + inv * acc[4]; o[5] = p2.y + inv * acc[5];
    o[6] = p3.x + inv * acc[6]; o[7] = p3.y + inv * acc[7];
    float ss = 0.0f;
#pragma unroll
    for (int k = 0; k < 8; k++) ss += o[k] * o[k];
    ss += __shfl_xor(ss, 1); ss += __shfl_xor(ss, 2);
    ss += __shfl_xor(ss, 4); ss += __shfl_xor(ss, 8);
    float r = 1.0f / fmaxf(sqrtf(ss), 1e-12f);
#pragma unroll
    for (int k = 0; k < 8; k++) o[k] *= r;
    if (lane < 16) {
        if constexpr (WRITE_F32) {
            ((float4*)OUTF)[(size_t)wave * 32 + q * 2]     = make_float4(o[0], o[1], o[2], o[3]);
            ((float4*)OUTF)[(size_t)wave * 32 + q * 2 + 1] = make_float4(o[4], o[5], o[6], o[7]);
        }
        uint4 u;
        u.x = packbf2(o[0], o[1]); u.y = packbf2(o[2], o[3]);
        u.z = packbf2(o[4], o[5]); u.w = packbf2(o[6], o[7]);
        OUTB[(size_t)wave * ostride4 + ooff4 + q] = u;
    }
}

// ------------------------------------------- pure aggregation (bf16 in/out, 128-dim)
__global__ __launch_bounds__(256) void k_agg4(const uint4* __restrict__ IN,
                                              const int* __restrict__ slots,
                                              const int* __restrict__ cnt,
                                              uint4* __restrict__ OUT,
                                              int istride4, int ioff4, int ostride4, int ooff4) {
    const int wave = (blockIdx.x * blockDim.x + threadIdx.x) >> 6;
    const int lane = threadIdx.x & 63;
    if (wave >= N_NODES) return;
    const int q = lane & 15, sub = lane >> 4;
    int deg = cnt[wave];
    deg = min(deg, SLOT_CAP);
    const int base = wave * SLOT_CAP;
    float acc[8] = {};
    int i = sub;
    for (; i + 4 < deg; i += 8) {
        int nb0 = slots[base + i], nb1 = slots[base + i + 4];
        uint4 v0 = IN[(size_t)nb0 * istride4 + ioff4 + q];
        uint4 v1 = IN[(size_t)nb1 * istride4 + ioff4 + q];
        float2 a0 = bfu2f2(v0.x), a1 = bfu2f2(v0.y), a2 = bfu2f2(v0.z), a3 = bfu2f2(v0.w);
        float2 b0 = bfu2f2(v1.x), b1 = bfu2f2(v1.y), b2 = bfu2f2(v1.z), b3 = bfu2f2(v1.w);
        acc[0] += a0.x + b0.x; acc[1] += a0.y + b0.y;
        acc[2] += a1.x + b1.x; acc[3] += a1.y + b1.y;
        acc[4] += a2.x + b2.x; acc[5] += a2.y + b2.y;
        acc[6] += a3.x + b3.x; acc[7] += a3.y + b3.y;
    }
    if (i < deg) {
        int nb = slots[base + i];
        uint4 v = IN[(size_t)nb * istride4 + ioff4 + q];
        float2 a0 = bfu2f2(v.x), a1 = bfu2f2(v.y), a2 = bfu2f2(v.z), a3 = bfu2f2(v.w);
        acc[0] += a0.x; acc[1] += a0.y; acc[2] += a1.x; acc[3] += a1.y;
        acc[4] += a2.x; acc[5] += a2.y; acc[6] += a3.x; acc[7] += a3.y;
    }
#pragma unroll
    for (int k = 0; k < 8; k++) {
        acc[k] += __shfl_xor(acc[k], 16);
        acc[k] += __shfl_xor(acc[k], 32);
    }
    const float inv = 1.0f / fmaxf((float)deg, 1.0f);
    if (lane < 16) {
        uint4 u;
        u.x = packbf2(inv * acc[0], inv * acc[1]);
        u.y = packbf2(inv * acc[2], inv * acc[3]);
        u.z = packbf2(inv * acc[4], inv * acc[5]);
        u.w = packbf2(inv * acc[6], inv * acc[7]);
        OUT[(size_t)wave * ostride4 + ooff4 + q] = u;
    }
}

// ---------------------------------------------------------------- launch
extern "C" void kernel_launch(void* const* d_in, const int* in_sizes, int n_in,
                              void* d_out, int out_size, void* d_ws, size_t ws_size,
                              hipStream_t stream) {
    const float* feat  = (const float*)d_in[0];
    const int*   ei    = (const int*)d_in[1];
    const int*   src   = ei;
    const int*   dst   = ei + N_EDGES;
    const float* Wl_e1 = (const float*)d_in[2];
    const float* bl_e1 = (const float*)d_in[3];
    const float* Wr_e1 = (const float*)d_in[4];
    const float* Wl_e2 = (const float*)d_in[5];
    const float* bl_e2 = (const float*)d_in[6];
    const float* Wr_e2 = (const float*)d_in[7];
    const float* W_fc  = (const float*)d_in[8];
    const float* b_fc  = (const float*)d_in[9];
    const float* Wl_d1 = (const float*)d_in[10];
    const float* bl_d1 = (const float*)d_in[11];
    const float* Wr_d1 = (const float*)d_in[12];
    const float* Wl_d2 = (const float*)d_in[13];
    const float* bl_d2 = (const float*)d_in[14];
    const float* Wr_d2 = (const float*)d_in[15];

    char* w = (char*)d_ws;
    auto alloc = [&](size_t bytes) -> void* {
        void* p = (void*)w;
        w += (bytes + 255) & ~(size_t)255;
        return p;
    };
    int* cnt   = (int*)alloc((size_t)N_NODES * 4);
    int* slots = (int*)alloc((size_t)N_NODES * SLOT_CAP * 4);
    unsigned short* bfpool = (unsigned short*)alloc((size_t)PREP_TOT * 2);
    unsigned short* TP   = (unsigned short*)alloc((size_t)N_NODES * 256 * 2);  // [N][256] T||P
    unsigned short* hb   = (unsigned short*)alloc((size_t)N_NODES * 128 * 2);  // h, then xfc
    unsigned short* x1b  = (unsigned short*)alloc((size_t)N_NODES * 128 * 2);
    unsigned short* X2   = (unsigned short*)alloc((size_t)N_NODES * 256 * 2);  // [aggm || hd1]

    unsigned short* featb = bfpool;
    float* x1     = (float*)d_out;
    float* x1_rec = (float*)d_out + (size_t)N_NODES * 128;

    hipMemsetAsync(cnt, 0, (size_t)N_NODES * 4, stream);

    const int EB = (N_EDGES + 255) / 256;
    k_prep<<<2048, 256, 0, stream>>>(feat, Wl_e1, Wr_e1, Wl_e2, Wr_e2, W_fc, Wl_d1, Wr_d1, Wl_d2, Wr_d2, bfpool);
    k_fillslot<<<EB, 256, 0, stream>>>(src, dst, cnt, slots);

    const int NB128 = (N_NODES + 127) / 128;  // 391
    const int WPB   = (N_NODES * 64 + 255) / 256;

    // ---- encoder conv1: 256 -> 128 (fused T||P)
    k_gmm2<256><<<dim3(NB128, 2), 256, 0, stream>>>(featb, bfpool + O_WL_E1, nullptr, bl_e1, TP, N_NODES, 256);
    k_aggfin4<false><<<WPB, 256, 0, stream>>>((const uint4*)TP, slots, cnt, nullptr, (uint4*)hb, 16, 0);
    // ---- encoder conv2: 128 -> 128  (x1 f32 + bf16 copy)
    k_gmm2<128><<<dim3(NB128, 2), 256, 0, stream>>>(hb, bfpool + O_WL_E2, nullptr, bl_e2, TP, N_NODES, 256);
    k_aggfin4<true><<<WPB, 256, 0, stream>>>((const uint4*)TP, slots, cnt, x1, (uint4*)x1b, 16, 0);
    // ---- bottleneck fc: 128 -> 128 (hb dead -> xfc)
    k_gmm2<128><<<dim3(NB128, 1), 256, 0, stream>>>(x1b, bfpool + O_W_FC, b_fc, nullptr, hb, N_NODES, 128);
    // ---- decoder conv1: 128 -> 128 (hd1 -> X2 cols 128-255)
    k_gmm2<128><<<dim3(NB128, 2), 256, 0, stream>>>(hb, bfpool + O_WL_D1, nullptr, bl_d1, TP, N_NODES, 256);
    k_aggfin4<false><<<WPB, 256, 0, stream>>>((const uint4*)TP, slots, cnt, nullptr, (uint4*)X2, 32, 16);
    // ---- decoder conv2: 128 -> 256 (agg-first into X2 cols 0-127; fused GEMM+norm -> x1_rec)
    k_agg4<<<WPB, 256, 0, stream>>>((const uint4*)X2, slots, cnt, (uint4*)X2, 32, 16, 32, 0);
    k_gmmn<<<NB128, 256, 0, stream>>>(X2, bfpool + O_D2, bl_d2, x1_rec, N_NODES);
}